// Round 1
// baseline (862.874 us; speedup 1.0000x reference)
//
#include <hip/hip_runtime.h>
#include <stdint.h>

typedef __attribute__((ext_vector_type(8))) short short8;
typedef __attribute__((ext_vector_type(4))) float f32x4;

#define K_IN 4096
#define N_OUT 4096
#define KEFF 8192

// round-to-nearest-even fp32 -> bf16 bits
__device__ __forceinline__ unsigned short f2bf(float f) {
  unsigned u = __builtin_bit_cast(unsigned, f);
  u += 0x7FFFu + ((u >> 16) & 1u);
  return (unsigned short)(u >> 16);
}

// W''[o][k] = W''[o][k+4096] = bf16(q[o][k] - zp[o])  (exact: small integers)
__global__ void prep_w_kernel(const int* __restrict__ q, const float* __restrict__ zp,
                              unsigned short* __restrict__ W) {
  size_t t = (size_t)blockIdx.x * blockDim.x + threadIdx.x;
  size_t base = t * 8;                       // element index in [0, 4096*4096)
  int o = (int)(base >> 12);
  int k = (int)(base & 4095);
  float z = zp[o];
  int4 q0 = *(const int4*)(q + base);
  int4 q1 = *(const int4*)(q + base + 4);
  int v[8] = {q0.x, q0.y, q0.z, q0.w, q1.x, q1.y, q1.z, q1.w};
  short8 o8;
#pragma unroll
  for (int j = 0; j < 8; ++j) {
    float f = (float)v[j] - z;               // integer in [-10, 9], exact in bf16
    o8[j] = (short)(__builtin_bit_cast(unsigned, f) >> 16);
  }
  size_t row = (size_t)o * KEFF;
  *(short8*)(W + row + k) = o8;
  *(short8*)(W + row + 4096 + k) = o8;
}

// A''[m][k] = bf16_hi(x[m][k]); A''[m][k+4096] = bf16(x - hi)
__global__ void prep_a_kernel(const float* __restrict__ x, unsigned short* __restrict__ A) {
  size_t t = (size_t)blockIdx.x * blockDim.x + threadIdx.x;
  size_t base = t * 8;                       // element index in [0, M*4096)
  size_t m = base >> 12;
  int k = (int)(base & 4095);
  float4 x0 = *(const float4*)(x + base);
  float4 x1 = *(const float4*)(x + base + 4);
  float xs[8] = {x0.x, x0.y, x0.z, x0.w, x1.x, x1.y, x1.z, x1.w};
  short8 hi8, lo8;
#pragma unroll
  for (int j = 0; j < 8; ++j) {
    unsigned short h = f2bf(xs[j]);
    float hf = __builtin_bit_cast(float, (unsigned)h << 16);
    hi8[j] = (short)h;
    lo8[j] = (short)f2bf(xs[j] - hf);
  }
  size_t row = m * KEFF;
  *(short8*)(A + row + k) = hi8;
  *(short8*)(A + row + 4096 + k) = lo8;
}

// m97-structure GEMM: 128x128 tile, BK=64, 4 waves (2x2 of 64x64),
// 16x16x32 bf16 MFMA, global_load_lds width 16, 2-barrier loop.
// A: [M][KEFF] bf16 row-major; B: [N][KEFF] bf16 row-major (B^T layout).
__global__ __launch_bounds__(256) void gemm_kernel(const unsigned short* __restrict__ A,
                                                   const unsigned short* __restrict__ B,
                                                   const float* __restrict__ scale,
                                                   float* __restrict__ C) {
  __shared__ unsigned short Al[128 * 64];
  __shared__ unsigned short Bl[128 * 64];
  const int tid = threadIdx.x;
  const int lane = tid & 63;
  const int brow = blockIdx.y * 128;         // m
  const int bcol = blockIdx.x * 128;         // n
  const int wr = ((tid >> 7) & 1) * 64;      // wave row (wid>>1)
  const int wc = ((tid >> 6) & 1) * 64;      // wave col (wid&1)

  // staging: inst i covers rows i*32..i*32+31; thread t -> row t/8, cols (t%8)*8..+7
  const int srow = tid >> 3;
  const int scol = (tid & 7) * 8;
  const int wbase = (tid & 192) * 8;         // wave-uniform LDS base (wid*512 elems)

  const unsigned short* Ag = A + (size_t)(brow + srow) * KEFF + scol;
  const unsigned short* Bg = B + (size_t)(bcol + srow) * KEFF + scol;

  const int fr = lane & 15;                  // fragment row
  const int fk = (lane >> 4) * 8;            // fragment k offset

  f32x4 acc[4][4];
#pragma unroll
  for (int i = 0; i < 4; ++i)
#pragma unroll
    for (int j = 0; j < 4; ++j) acc[i][j] = (f32x4){0.f, 0.f, 0.f, 0.f};

  for (int kt = 0; kt < KEFF; kt += 64) {
#pragma unroll
    for (int i = 0; i < 4; ++i) {
      __builtin_amdgcn_global_load_lds(
          (const __attribute__((address_space(1))) void*)(Ag + kt + (size_t)i * 32 * KEFF),
          (__attribute__((address_space(3))) void*)(Al + i * 2048 + wbase), 16, 0, 0);
      __builtin_amdgcn_global_load_lds(
          (const __attribute__((address_space(1))) void*)(Bg + kt + (size_t)i * 32 * KEFF),
          (__attribute__((address_space(3))) void*)(Bl + i * 2048 + wbase), 16, 0, 0);
    }
    __syncthreads();   // drains vmcnt -> LDS tiles ready
#pragma unroll
    for (int kk = 0; kk < 64; kk += 32) {
      short8 af[4], bfr[4];
#pragma unroll
      for (int mi = 0; mi < 4; ++mi)
        af[mi] = *(const short8*)&Al[(wr + mi * 16 + fr) * 64 + kk + fk];
#pragma unroll
      for (int ni = 0; ni < 4; ++ni)
        bfr[ni] = *(const short8*)&Bl[(wc + ni * 16 + fr) * 64 + kk + fk];
#pragma unroll
      for (int mi = 0; mi < 4; ++mi)
#pragma unroll
        for (int ni = 0; ni < 4; ++ni)
          acc[mi][ni] = __builtin_amdgcn_mfma_f32_16x16x32_bf16(af[mi], bfr[ni], acc[mi][ni], 0, 0, 0);
    }
    __syncthreads();   // before next stage overwrites LDS
  }

  // epilogue: D col = lane&15 (n), row = (lane>>4)*4 + r (m); y = acc * scale[n]
  const int r0 = brow + wr + ((lane >> 4) << 2);
  const int c0 = bcol + wc + (lane & 15);
#pragma unroll
  for (int ni = 0; ni < 4; ++ni) {
    float s = scale[c0 + ni * 16];
#pragma unroll
    for (int mi = 0; mi < 4; ++mi) {
#pragma unroll
      for (int r = 0; r < 4; ++r)
        C[(size_t)(r0 + mi * 16 + r) * N_OUT + c0 + ni * 16] = acc[mi][ni][r] * s;
    }
  }
}

// correctness safety net if ws_size is too small for the staged path
__global__ void fallback_kernel(const float* __restrict__ x, const float* __restrict__ scale,
                                const float* __restrict__ zp, const int* __restrict__ q,
                                float* __restrict__ y) {
  int o = blockIdx.x * blockDim.x + threadIdx.x;
  int m = blockIdx.y;
  float z = zp[o];
  const int* qr = q + (size_t)o * K_IN;
  const float* xr = x + (size_t)m * K_IN;
  float acc = 0.f;
  for (int k = 0; k < K_IN; k += 4) {
    int4 qq = *(const int4*)(qr + k);
    float4 xx = *(const float4*)(xr + k);
    acc += xx.x * ((float)qq.x - z) + xx.y * ((float)qq.y - z)
         + xx.z * ((float)qq.z - z) + xx.w * ((float)qq.w - z);
  }
  y[(size_t)m * N_OUT + o] = acc * scale[o];
}

extern "C" void kernel_launch(void* const* d_in, const int* in_sizes, int n_in,
                              void* d_out, int out_size, void* d_ws, size_t ws_size,
                              hipStream_t stream) {
  const float* x     = (const float*)d_in[0];
  const float* scale = (const float*)d_in[1];
  const float* zp    = (const float*)d_in[2];
  const int*   q     = (const int*)d_in[3];
  float* y = (float*)d_out;
  const int M = in_sizes[0] / K_IN;          // 8192

  size_t wbytes = (size_t)N_OUT * KEFF * 2;  //  64 MiB
  size_t abytes = (size_t)M * KEFF * 2;      // 128 MiB
  if (ws_size >= wbytes + abytes) {
    unsigned short* W = (unsigned short*)d_ws;
    unsigned short* A = W + (size_t)N_OUT * KEFF;
    unsigned gw = (unsigned)(((size_t)N_OUT * K_IN) / (8 * 256));
    unsigned ga = (unsigned)(((size_t)M * K_IN) / (8 * 256));
    prep_w_kernel<<<gw, 256, 0, stream>>>(q, zp, W);
    prep_a_kernel<<<ga, 256, 0, stream>>>(x, A);
    dim3 grid(N_OUT / 128, M / 128);
    gemm_kernel<<<grid, 256, 0, stream>>>(A, W, scale, y);
  } else {
    dim3 grid(N_OUT / 256, M);
    fallback_kernel<<<grid, 256, 0, stream>>>(x, scale, zp, q, y);
  }
}

// Round 5
// 686.736 us; speedup vs baseline: 1.2565x; 1.2565x over previous
//
#include <hip/hip_runtime.h>
#include <stdint.h>

typedef __attribute__((ext_vector_type(8))) short short8;
typedef __attribute__((ext_vector_type(4))) float f32x4;

#define K_IN 4096
#define N_OUT 4096
#define KEFF 8192

// round-to-nearest-even fp32 -> bf16 bits
__device__ __forceinline__ unsigned short f2bf(float f) {
  unsigned u = __builtin_bit_cast(unsigned, f);
  u += 0x7FFFu + ((u >> 16) & 1u);
  return (unsigned short)(u >> 16);
}

// W''[o][k] = W''[o][k+4096] = bf16(q[o][k] - zp[o])  (exact: small integers)
__global__ void prep_w_kernel(const int* __restrict__ q, const float* __restrict__ zp,
                              unsigned short* __restrict__ W) {
  size_t t = (size_t)blockIdx.x * blockDim.x + threadIdx.x;
  size_t base = t * 8;                       // element index in [0, 4096*4096)
  int o = (int)(base >> 12);
  int k = (int)(base & 4095);
  float z = zp[o];
  int4 q0 = *(const int4*)(q + base);
  int4 q1 = *(const int4*)(q + base + 4);
  int v[8] = {q0.x, q0.y, q0.z, q0.w, q1.x, q1.y, q1.z, q1.w};
  short8 o8;
#pragma unroll
  for (int j = 0; j < 8; ++j) {
    float f = (float)v[j] - z;               // integer in [-10, 9], exact in bf16
    o8[j] = (short)(__builtin_bit_cast(unsigned, f) >> 16);
  }
  size_t row = (size_t)o * KEFF;
  *(short8*)(W + row + k) = o8;
  *(short8*)(W + row + 4096 + k) = o8;
}

// A''[m][k] = bf16_hi(x[m][k]); A''[m][k+4096] = bf16(x - hi)
__global__ void prep_a_kernel(const float* __restrict__ x, unsigned short* __restrict__ A) {
  size_t t = (size_t)blockIdx.x * blockDim.x + threadIdx.x;
  size_t base = t * 8;                       // element index in [0, M*4096)
  size_t m = base >> 12;
  int k = (int)(base & 4095);
  float4 x0 = *(const float4*)(x + base);
  float4 x1 = *(const float4*)(x + base + 4);
  float xs[8] = {x0.x, x0.y, x0.z, x0.w, x1.x, x1.y, x1.z, x1.w};
  short8 hi8, lo8;
#pragma unroll
  for (int j = 0; j < 8; ++j) {
    unsigned short h = f2bf(xs[j]);
    float hf = __builtin_bit_cast(float, (unsigned)h << 16);
    hi8[j] = (short)h;
    lo8[j] = (short)f2bf(xs[j] - hf);
  }
  size_t row = m * KEFF;
  *(short8*)(A + row + k) = hi8;
  *(short8*)(A + row + 4096 + k) = lo8;
}

// m97-structure GEMM + T2 XOR-swizzle (rule #21: linear LDS dest via
// global_load_lds, inverse-swizzled GLOBAL source, swizzled ds_read).
// Swizzle: 16B-chunk c of row r holds global chunk c ^ (r&7).
// A: [M][KEFF] bf16 row-major; B: [N][KEFF] bf16 row-major (B^T layout).
__global__ __launch_bounds__(256) void gemm_kernel(const unsigned short* __restrict__ A,
                                                   const unsigned short* __restrict__ B,
                                                   const float* __restrict__ scale,
                                                   float* __restrict__ C) {
  __shared__ unsigned short Al[128 * 64];
  __shared__ unsigned short Bl[128 * 64];
  const int tid = threadIdx.x;
  const int lane = tid & 63;
  const int brow = blockIdx.y * 128;         // m
  const int bcol = blockIdx.x * 128;         // n
  const int wr = ((tid >> 7) & 1) * 64;      // wave row (wid>>1)
  const int wc = ((tid >> 6) & 1) * 64;      // wave col (wid&1)

  // staging: inst i covers rows i*32..+31; thread t -> row t/8.
  // Pre-swizzled source: global chunk = (t&7) ^ (row&7); LDS dest stays linear.
  const int srow = tid >> 3;
  const int schunk = (tid & 7) ^ (srow & 7); // (row&7) invariant under +32
  const int scol = schunk * 8;
  const int wbase = (tid & 192) * 8;         // wave-uniform LDS base

  const unsigned short* Ag = A + (size_t)(brow + srow) * KEFF + scol;
  const unsigned short* Bg = B + (size_t)(bcol + srow) * KEFF + scol;

  const int fr = lane & 15;                  // fragment row
  const int fk = (lane >> 4) * 8;            // fragment k offset (elems)
  const int fswz = (fr & 7) << 3;            // read-side XOR, elem-granular

  f32x4 acc[4][4];
#pragma unroll
  for (int i = 0; i < 4; ++i)
#pragma unroll
    for (int j = 0; j < 4; ++j) acc[i][j] = (f32x4){0.f, 0.f, 0.f, 0.f};

  for (int kt = 0; kt < KEFF; kt += 64) {
#pragma unroll
    for (int i = 0; i < 4; ++i) {
      __builtin_amdgcn_global_load_lds(
          (const __attribute__((address_space(1))) void*)(Ag + kt + (size_t)i * 32 * KEFF),
          (__attribute__((address_space(3))) void*)(Al + i * 2048 + wbase), 16, 0, 0);
      __builtin_amdgcn_global_load_lds(
          (const __attribute__((address_space(1))) void*)(Bg + kt + (size_t)i * 32 * KEFF),
          (__attribute__((address_space(3))) void*)(Bl + i * 2048 + wbase), 16, 0, 0);
    }
    __syncthreads();   // drains vmcnt -> LDS tiles ready
#pragma unroll
    for (int kk = 0; kk < 64; kk += 32) {
      short8 af[4], bfr[4];
#pragma unroll
      for (int mi = 0; mi < 4; ++mi)
        af[mi] = *(const short8*)&Al[(wr + mi * 16 + fr) * 64 + ((kk + fk) ^ fswz)];
#pragma unroll
      for (int ni = 0; ni < 4; ++ni)
        bfr[ni] = *(const short8*)&Bl[(wc + ni * 16 + fr) * 64 + ((kk + fk) ^ fswz)];
#pragma unroll
      for (int mi = 0; mi < 4; ++mi)
#pragma unroll
        for (int ni = 0; ni < 4; ++ni)
          acc[mi][ni] = __builtin_amdgcn_mfma_f32_16x16x32_bf16(af[mi], bfr[ni], acc[mi][ni], 0, 0, 0);
    }
    __syncthreads();   // before next stage overwrites LDS
  }

  // epilogue: D col = lane&15 (n), row = (lane>>4)*4 + r (m); y = acc * scale[n]
  const int r0 = brow + wr + ((lane >> 4) << 2);
  const int c0 = bcol + wc + (lane & 15);
#pragma unroll
  for (int ni = 0; ni < 4; ++ni) {
    float s = scale[c0 + ni * 16];
#pragma unroll
    for (int mi = 0; mi < 4; ++mi) {
#pragma unroll
      for (int r = 0; r < 4; ++r)
        C[(size_t)(r0 + mi * 16 + r) * N_OUT + c0 + ni * 16] = acc[mi][ni][r] * s;
    }
  }
}

// correctness safety net if ws_size is too small for the staged path
__global__ void fallback_kernel(const float* __restrict__ x, const float* __restrict__ scale,
                                const float* __restrict__ zp, const int* __restrict__ q,
                                float* __restrict__ y) {
  int o = blockIdx.x * blockDim.x + threadIdx.x;
  int m = blockIdx.y;
  float z = zp[o];
  const int* qr = q + (size_t)o * K_IN;
  const float* xr = x + (size_t)m * K_IN;
  float acc = 0.f;
  for (int k = 0; k < K_IN; k += 4) {
    int4 qq = *(const int4*)(qr + k);
    float4 xx = *(const float4*)(xr + k);
    acc += xx.x * ((float)qq.x - z) + xx.y * ((float)qq.y - z)
         + xx.z * ((float)qq.z - z) + xx.w * ((float)qq.w - z);
  }
  y[(size_t)m * N_OUT + o] = acc * scale[o];
}

extern "C" void kernel_launch(void* const* d_in, const int* in_sizes, int n_in,
                              void* d_out, int out_size, void* d_ws, size_t ws_size,
                              hipStream_t stream) {
  const float* x     = (const float*)d_in[0];
  const float* scale = (const float*)d_in[1];
  const float* zp    = (const float*)d_in[2];
  const int*   q     = (const int*)d_in[3];
  float* y = (float*)d_out;
  const int M = in_sizes[0] / K_IN;          // 8192

  size_t wbytes = (size_t)N_OUT * KEFF * 2;  //  64 MiB
  size_t abytes = (size_t)M * KEFF * 2;      // 128 MiB
  if (ws_size >= wbytes + abytes) {
    unsigned short* W = (unsigned short*)d_ws;
    unsigned short* A = W + (size_t)N_OUT * KEFF;
    unsigned gw = (unsigned)(((size_t)N_OUT * K_IN) / (8 * 256));
    unsigned ga = (unsigned)(((size_t)M * K_IN) / (8 * 256));
    prep_w_kernel<<<gw, 256, 0, stream>>>(q, zp, W);
    prep_a_kernel<<<ga, 256, 0, stream>>>(x, A);
    dim3 grid(N_OUT / 128, M / 128);
    gemm_kernel<<<grid, 256, 0, stream>>>(A, W, scale, y);
  } else {
    dim3 grid(N_OUT / 256, M);
    fallback_kernel<<<grid, 256, 0, stream>>>(x, scale, zp, q, y);
  }
}

// Round 6
// 483.713 us; speedup vs baseline: 1.7839x; 1.4197x over previous
//
#include <hip/hip_runtime.h>
#include <stdint.h>

typedef __attribute__((ext_vector_type(8))) short short8;
typedef __attribute__((ext_vector_type(4))) float f32x4;

#define K_IN 4096
#define N_OUT 4096
#define KEFF 8192
#define NKT 128            // K-tiles of 64
#define ITERS 64           // 2 K-tiles per iteration

// round-to-nearest-even fp32 -> bf16 bits
__device__ __forceinline__ unsigned short f2bf(float f) {
  unsigned u = __builtin_bit_cast(unsigned, f);
  u += 0x7FFFu + ((u >> 16) & 1u);
  return (unsigned short)(u >> 16);
}

// W''[o][k] = W''[o][k+4096] = bf16(q[o][k] - zp[o])  (exact: small integers)
__global__ void prep_w_kernel(const int* __restrict__ q, const float* __restrict__ zp,
                              unsigned short* __restrict__ W) {
  size_t t = (size_t)blockIdx.x * blockDim.x + threadIdx.x;
  size_t base = t * 8;
  int o = (int)(base >> 12);
  int k = (int)(base & 4095);
  float z = zp[o];
  int4 q0 = *(const int4*)(q + base);
  int4 q1 = *(const int4*)(q + base + 4);
  int v[8] = {q0.x, q0.y, q0.z, q0.w, q1.x, q1.y, q1.z, q1.w};
  short8 o8;
#pragma unroll
  for (int j = 0; j < 8; ++j) {
    float f = (float)v[j] - z;
    o8[j] = (short)(__builtin_bit_cast(unsigned, f) >> 16);
  }
  size_t row = (size_t)o * KEFF;
  *(short8*)(W + row + k) = o8;
  *(short8*)(W + row + 4096 + k) = o8;
}

// A''[m][k] = bf16_hi(x[m][k]); A''[m][k+4096] = bf16(x - hi)
__global__ void prep_a_kernel(const float* __restrict__ x, unsigned short* __restrict__ A) {
  size_t t = (size_t)blockIdx.x * blockDim.x + threadIdx.x;
  size_t base = t * 8;
  size_t m = base >> 12;
  int k = (int)(base & 4095);
  float4 x0 = *(const float4*)(x + base);
  float4 x1 = *(const float4*)(x + base + 4);
  float xs[8] = {x0.x, x0.y, x0.z, x0.w, x1.x, x1.y, x1.z, x1.w};
  short8 hi8, lo8;
#pragma unroll
  for (int j = 0; j < 8; ++j) {
    unsigned short h = f2bf(xs[j]);
    float hf = __builtin_bit_cast(float, (unsigned)h << 16);
    hi8[j] = (short)h;
    lo8[j] = (short)f2bf(xs[j] - hf);
  }
  size_t row = m * KEFF;
  *(short8*)(A + row + k) = hi8;
  *(short8*)(A + row + 4096 + k) = lo8;
}

// ---------------------------------------------------------------------------
// 256x256 8-phase GEMM (T2 swizzle + T3/T4 counted-vmcnt pipeline + T5 setprio)
// A: [M][KEFF] bf16 rm; B: [N][KEFF] bf16 rm (B^T). 8 waves (2M x 4N), BK=64.
// LDS 128 KiB: A[2][256][64] + B[2][256][64]. Stage unit = 64 rows x 64 cols
// (8 KiB = 1 global_load_lds per thread); 2 units staged per phase.
// Swizzle: 16B-chunk c of row r holds global chunk c ^ (r&7); linear LDS dest,
// inverse-swizzled global source (rule #21).
// vmcnt(6) only at phases 4 and 8 (3 units = 6 loads stay in flight).
// ---------------------------------------------------------------------------
#define A0OFF 0
#define A1OFF 16384
#define B0OFF 32768
#define B1OFF 49152

// stage one 64x64 unit of matrix at gbase (tile-row base), K-tile kt, unit u
#define STAGE(gbase, kt, u, ldsOff)                                              \
  __builtin_amdgcn_global_load_lds(                                              \
      (const __attribute__((address_space(1))) void*)((gbase) +                  \
          (size_t)(u) * 64 * KEFF + (size_t)(kt) * 64 + laneOff),                \
      (__attribute__((address_space(3))) void*)(lds + (ldsOff) + (u) * 4096 +    \
          wid * 512), 16, 0, 0);

// one phase: ds-read A subtile (+B at q==0) || stage 2 units -> barrier ->
// lgkmcnt(0) -> 16 MFMA (setprio) -> [vmcnt(6)] -> barrier
#define PHASE(ABOFF, BBOFF, q, STAGE_CODE, DOVM)                                 \
  {                                                                              \
    short8 af[2][2];                                                             \
    _Pragma("unroll") for (int m2 = 0; m2 < 2; ++m2)                             \
      _Pragma("unroll") for (int kc = 0; kc < 2; ++kc)                           \
        af[m2][kc] = *(const short8*)&lds[(ABOFF) +                              \
            (wmBase + ((q) * 2 + m2) * 16 + fr) * 64 + ((kc * 32 + fk) ^ fswz)]; \
    if ((q) == 0) {                                                              \
      _Pragma("unroll") for (int n = 0; n < 4; ++n)                              \
        _Pragma("unroll") for (int kc = 0; kc < 2; ++kc)                         \
          bf[n][kc] = *(const short8*)&lds[(BBOFF) +                             \
              (wnBase + n * 16 + fr) * 64 + ((kc * 32 + fk) ^ fswz)];            \
    }                                                                            \
    STAGE_CODE;                                                                  \
    __builtin_amdgcn_s_barrier();                                                \
    asm volatile("s_waitcnt lgkmcnt(0)" ::: "memory");                           \
    __builtin_amdgcn_sched_barrier(0);                                           \
    __builtin_amdgcn_s_setprio(1);                                               \
    _Pragma("unroll") for (int kc = 0; kc < 2; ++kc)                             \
      _Pragma("unroll") for (int m2 = 0; m2 < 2; ++m2)                           \
        _Pragma("unroll") for (int n = 0; n < 4; ++n)                            \
          acc[(q) * 2 + m2][n] = __builtin_amdgcn_mfma_f32_16x16x32_bf16(        \
              af[m2][kc], bf[n][kc], acc[(q) * 2 + m2][n], 0, 0, 0);             \
    __builtin_amdgcn_s_setprio(0);                                               \
    if (DOVM) {                                                                  \
      asm volatile("s_waitcnt vmcnt(6)" ::: "memory");                           \
      __builtin_amdgcn_sched_barrier(0);                                         \
    }                                                                            \
    __builtin_amdgcn_s_barrier();                                                \
  }

__global__ __launch_bounds__(512, 2) void gemm_kernel(
    const unsigned short* __restrict__ A, const unsigned short* __restrict__ B,
    const float* __restrict__ scale, float* __restrict__ C) {
  __shared__ unsigned short lds[65536];     // 128 KiB

  const int tid = threadIdx.x;
  const int lane = tid & 63;
  const int wid = tid >> 6;                 // 0..7
  const int wmBase = (wid >> 2) * 128;      // wave M offset in tile
  const int wnBase = (wid & 3) * 64;        // wave N offset in tile

  // XCD-aware bijective swizzle: 512 blocks, 512 % 8 == 0
  const int bid = blockIdx.x;
  const int swz = (bid & 7) * 64 + (bid >> 3);
  const int tn = swz & 15;                  // 16 N-tiles
  const int tm = swz >> 4;                  // 32 M-tiles

  const unsigned short* Ag = A + (size_t)tm * 256 * KEFF;
  const unsigned short* Bg = B + (size_t)tn * 256 * KEFF;

  // per-lane staging source offset: row-in-unit = wid*8 + lane/8,
  // global col chunk = (lane&7) ^ (lane>>3)  (inverse swizzle)
  const size_t laneOff =
      (size_t)(wid * 8 + (lane >> 3)) * KEFF + 8 * ((lane & 7) ^ (lane >> 3));

  // fragment addressing
  const int fr = lane & 15;
  const int fk = (lane >> 4) * 8;
  const int fswz = (fr & 7) << 3;

  f32x4 acc[8][4];
#pragma unroll
  for (int i = 0; i < 8; ++i)
#pragma unroll
    for (int j = 0; j < 4; ++j) acc[i][j] = (f32x4){0.f, 0.f, 0.f, 0.f};
  short8 bf[4][2];

  // ---- prologue: K-tile 0 full (8 loads) + K-tile 1 B all, A u0,u2 (6 loads)
  STAGE(Ag, 0, 0, A0OFF); STAGE(Ag, 0, 1, A0OFF);
  STAGE(Ag, 0, 2, A0OFF); STAGE(Ag, 0, 3, A0OFF);
  STAGE(Bg, 0, 0, B0OFF); STAGE(Bg, 0, 1, B0OFF);
  STAGE(Bg, 0, 2, B0OFF); STAGE(Bg, 0, 3, B0OFF);
  STAGE(Bg, 1, 0, B1OFF); STAGE(Bg, 1, 1, B1OFF);
  STAGE(Bg, 1, 2, B1OFF); STAGE(Bg, 1, 3, B1OFF);
  STAGE(Ag, 1, 0, A1OFF); STAGE(Ag, 1, 2, A1OFF);
  asm volatile("s_waitcnt vmcnt(6)" ::: "memory");   // K-tile 0 landed
  __builtin_amdgcn_sched_barrier(0);
  __builtin_amdgcn_s_barrier();

  for (int t = 0; t < ITERS; ++t) {
    const int kt1 = 2 * t + 1;               // <= 127, no wrap
    const int kt2 = (2 * t + 2) & (NKT - 1); // wrap: harmless dead prefetch
    const int kt3 = (2 * t + 3) & (NKT - 1); //        in the last iteration

    // phases 1-4: consume buf0 (K-tile 2t)
    PHASE(A0OFF, B0OFF, 0, { STAGE(Ag, kt1, 1, A1OFF); STAGE(Ag, kt1, 3, A1OFF); }, 0)
    PHASE(A0OFF, B0OFF, 1, { STAGE(Bg, kt2, 0, B0OFF); STAGE(Bg, kt2, 1, B0OFF); }, 0)
    PHASE(A0OFF, B0OFF, 2, { STAGE(Bg, kt2, 2, B0OFF); STAGE(Bg, kt2, 3, B0OFF); }, 0)
    PHASE(A0OFF, B0OFF, 3, { STAGE(Ag, kt2, 0, A0OFF); STAGE(Ag, kt2, 2, A0OFF); }, 1)
    // phases 5-8: consume buf1 (K-tile 2t+1)
    PHASE(A1OFF, B1OFF, 0, { STAGE(Ag, kt2, 1, A0OFF); STAGE(Ag, kt2, 3, A0OFF); }, 0)
    PHASE(A1OFF, B1OFF, 1, { STAGE(Bg, kt3, 0, B1OFF); STAGE(Bg, kt3, 1, B1OFF); }, 0)
    PHASE(A1OFF, B1OFF, 2, { STAGE(Bg, kt3, 2, B1OFF); STAGE(Bg, kt3, 3, B1OFF); }, 0)
    PHASE(A1OFF, B1OFF, 3, { STAGE(Ag, kt3, 0, A1OFF); STAGE(Ag, kt3, 2, A1OFF); }, 1)
  }

  // epilogue: row = (lane>>4)*4 + r (+mi*16), col = lane&15 (+ni*16)
  const int r0 = tm * 256 + wmBase + ((lane >> 4) << 2);
  const int c0 = tn * 256 + wnBase + (lane & 15);
#pragma unroll
  for (int n = 0; n < 4; ++n) {
    float s = scale[c0 + n * 16];
#pragma unroll
    for (int m = 0; m < 8; ++m)
#pragma unroll
      for (int r = 0; r < 4; ++r)
        C[(size_t)(r0 + m * 16 + r) * N_OUT + c0 + n * 16] = acc[m][n][r] * s;
  }
}

// correctness safety net if ws_size is too small for the staged path
__global__ void fallback_kernel(const float* __restrict__ x, const float* __restrict__ scale,
                                const float* __restrict__ zp, const int* __restrict__ q,
                                float* __restrict__ y) {
  int o = blockIdx.x * blockDim.x + threadIdx.x;
  int m = blockIdx.y;
  float z = zp[o];
  const int* qr = q + (size_t)o * K_IN;
  const float* xr = x + (size_t)m * K_IN;
  float acc = 0.f;
  for (int k = 0; k < K_IN; k += 4) {
    int4 qq = *(const int4*)(qr + k);
    float4 xx = *(const float4*)(xr + k);
    acc += xx.x * ((float)qq.x - z) + xx.y * ((float)qq.y - z)
         + xx.z * ((float)qq.z - z) + xx.w * ((float)qq.w - z);
  }
  y[(size_t)m * N_OUT + o] = acc * scale[o];
}

extern "C" void kernel_launch(void* const* d_in, const int* in_sizes, int n_in,
                              void* d_out, int out_size, void* d_ws, size_t ws_size,
                              hipStream_t stream) {
  const float* x     = (const float*)d_in[0];
  const float* scale = (const float*)d_in[1];
  const float* zp    = (const float*)d_in[2];
  const int*   q     = (const int*)d_in[3];
  float* y = (float*)d_out;
  const int M = in_sizes[0] / K_IN;          // 8192

  size_t wbytes = (size_t)N_OUT * KEFF * 2;  //  64 MiB
  size_t abytes = (size_t)M * KEFF * 2;      // 128 MiB
  if (ws_size >= wbytes + abytes && (M % 256) == 0) {
    unsigned short* W = (unsigned short*)d_ws;
    unsigned short* Abuf = W + (size_t)N_OUT * KEFF;
    unsigned gw = (unsigned)(((size_t)N_OUT * K_IN) / (8 * 256));
    unsigned ga = (unsigned)(((size_t)M * K_IN) / (8 * 256));
    prep_w_kernel<<<gw, 256, 0, stream>>>(q, zp, W);
    prep_a_kernel<<<ga, 256, 0, stream>>>(x, Abuf);
    unsigned nblocks = (unsigned)((M / 256) * (N_OUT / 256));  // 512
    gemm_kernel<<<nblocks, 512, 0, stream>>>(Abuf, W, scale, y);
  } else {
    dim3 grid(N_OUT / 256, M);
    fallback_kernel<<<grid, 256, 0, stream>>>(x, scale, zp, q, y);
  }
}

// Round 7
// 277.932 us; speedup vs baseline: 3.1046x; 1.7404x over previous
//
#include <hip/hip_runtime.h>
#include <stdint.h>

typedef __attribute__((ext_vector_type(4))) int int4v;

#define K_IN 4096
#define N_OUT 4096
#define NKT 64             // K-tiles of 128 i8 elems (32 hi + 32 lo)

// W_i8[o][k] = (int8)(q[o][k] - zp[o])  (exact, in [-10,9])
__global__ void prep_w_kernel(const int* __restrict__ q, const float* __restrict__ zp,
                              signed char* __restrict__ W) {
  size_t t = (size_t)blockIdx.x * blockDim.x + threadIdx.x;
  size_t base = t * 8;
  int o = (int)(base >> 12);
  int z = (int)zp[o];                        // zp is an integral float
  int4 q0 = *(const int4*)(q + base);
  int4 q1 = *(const int4*)(q + base + 4);
  int v[8] = {q0.x, q0.y, q0.z, q0.w, q1.x, q1.y, q1.z, q1.w};
  union { signed char c[8]; uint64_t u; } pk;
#pragma unroll
  for (int j = 0; j < 8; ++j) pk.c[j] = (signed char)(v[j] - z);
  *(uint64_t*)(W + (size_t)o * K_IN + (base & 4095)) = pk.u;
}

// X14 = clamp(round(x*1024), +-8191) = 128*hi + lo; A[m][k]=hi, A[m][4096+k]=lo
__global__ void prep_a_kernel(const float* __restrict__ x, signed char* __restrict__ A) {
  size_t t = (size_t)blockIdx.x * blockDim.x + threadIdx.x;
  size_t base = t * 8;
  size_t m = base >> 12;
  int k = (int)(base & 4095);
  float4 x0 = *(const float4*)(x + base);
  float4 x1 = *(const float4*)(x + base + 4);
  float xs[8] = {x0.x, x0.y, x0.z, x0.w, x1.x, x1.y, x1.z, x1.w};
  union { signed char c[8]; uint64_t u; } hp, lp;
#pragma unroll
  for (int j = 0; j < 8; ++j) {
    int X = __float2int_rn(xs[j] * 1024.0f);
    X = X > 8191 ? 8191 : (X < -8191 ? -8191 : X);
    int hi = (X + 64) >> 7;                  // in [-64,64]
    int lo = X - (hi << 7);                  // in [-64,63]
    hp.c[j] = (signed char)hi;
    lp.c[j] = (signed char)lo;
  }
  size_t row = m * (size_t)(2 * K_IN);
  *(uint64_t*)(A + row + k) = hp.u;
  *(uint64_t*)(A + row + K_IN + k) = lp.u;
}

// ---------------------------------------------------------------------------
// 256x256 8-phase i8 GEMM. A: [M][8192] i8 (hi|lo); B=W: [4096][4096] i8.
// BK=128 i8 (128 B/row — byte-identical layout/swizzle to the bf16 version).
// 8 waves (2M x 4N); LDS 128 KiB = A[2][256][128B] + B[2][256][128B].
// K-tiles 0..31 = hi slice, 32..63 = lo slice (B tile index = kt & 31).
// One i32 acc; acc <<= 7 between the two halves (exact).
// Swizzle: 16B-chunk c of row r holds global chunk c ^ (r&7); linear LDS dest,
// inverse-swizzled global source (rule #21). vmcnt(6) at phases 4/8 only.
// ---------------------------------------------------------------------------
#define A0OFF 0
#define A1OFF 32768
#define B0OFF 65536
#define B1OFF 98304

#define STAGE_A(kt, u, ldsOff)                                                   \
  __builtin_amdgcn_global_load_lds(                                              \
      (const __attribute__((address_space(1))) void*)(Ag +                       \
          (size_t)(u) * 64 * (2 * K_IN) + (size_t)(kt) * 128 + laneOffA),        \
      (__attribute__((address_space(3))) void*)(lds + (ldsOff) + (u) * 8192 +    \
          wid * 1024), 16, 0, 0);

#define STAGE_B(kt, u, ldsOff)                                                   \
  __builtin_amdgcn_global_load_lds(                                              \
      (const __attribute__((address_space(1))) void*)(Bg +                       \
          (size_t)(u) * 64 * K_IN + (size_t)((kt) & 31) * 128 + laneOffB),       \
      (__attribute__((address_space(3))) void*)(lds + (ldsOff) + (u) * 8192 +    \
          wid * 1024), 16, 0, 0);

// one phase: ds-read A subtile (+B at q==0) || stage 2 units -> barrier ->
// lgkmcnt(0) -> 16 MFMA (setprio) -> [vmcnt(6)] -> barrier
#define PHASE(ABOFF, BBOFF, q, STAGE_CODE, DOVM)                                 \
  {                                                                              \
    int4v af[2][2];                                                              \
    _Pragma("unroll") for (int m2 = 0; m2 < 2; ++m2)                             \
      _Pragma("unroll") for (int kc = 0; kc < 2; ++kc)                           \
        af[m2][kc] = *(const int4v*)&lds[(ABOFF) +                               \
            (wmBase + ((q) * 2 + m2) * 16 + fr) * 128 +                          \
            ((kc * 64 + fk16) ^ fswz)];                                          \
    if ((q) == 0) {                                                              \
      _Pragma("unroll") for (int n = 0; n < 4; ++n)                              \
        _Pragma("unroll") for (int kc = 0; kc < 2; ++kc)                         \
          bf[n][kc] = *(const int4v*)&lds[(BBOFF) +                              \
              (wnBase + n * 16 + fr) * 128 + ((kc * 64 + fk16) ^ fswz)];         \
    }                                                                            \
    STAGE_CODE;                                                                  \
    __builtin_amdgcn_s_barrier();                                                \
    asm volatile("s_waitcnt lgkmcnt(0)" ::: "memory");                           \
    __builtin_amdgcn_sched_barrier(0);                                           \
    __builtin_amdgcn_s_setprio(1);                                               \
    _Pragma("unroll") for (int kc = 0; kc < 2; ++kc)                             \
      _Pragma("unroll") for (int m2 = 0; m2 < 2; ++m2)                           \
        _Pragma("unroll") for (int n = 0; n < 4; ++n)                            \
          acc[(q) * 2 + m2][n] = __builtin_amdgcn_mfma_i32_16x16x64_i8(          \
              af[m2][kc], bf[n][kc], acc[(q) * 2 + m2][n], 0, 0, 0);             \
    __builtin_amdgcn_s_setprio(0);                                               \
    if (DOVM) {                                                                  \
      asm volatile("s_waitcnt vmcnt(6)" ::: "memory");                           \
      __builtin_amdgcn_sched_barrier(0);                                         \
    }                                                                            \
    __builtin_amdgcn_s_barrier();                                                \
  }

#define ITERBODY(t)                                                              \
  {                                                                              \
    const int kt1 = 2 * (t) + 1;                                                 \
    const int kt2 = (2 * (t) + 2) & (NKT - 1);                                   \
    const int kt3 = (2 * (t) + 3) & (NKT - 1);                                   \
    PHASE(A0OFF, B0OFF, 0, { STAGE_A(kt1, 1, A1OFF); STAGE_A(kt1, 3, A1OFF); }, 0) \
    PHASE(A0OFF, B0OFF, 1, { STAGE_B(kt2, 0, B0OFF); STAGE_B(kt2, 1, B0OFF); }, 0) \
    PHASE(A0OFF, B0OFF, 2, { STAGE_B(kt2, 2, B0OFF); STAGE_B(kt2, 3, B0OFF); }, 0) \
    PHASE(A0OFF, B0OFF, 3, { STAGE_A(kt2, 0, A0OFF); STAGE_A(kt2, 2, A0OFF); }, 1) \
    PHASE(A1OFF, B1OFF, 0, { STAGE_A(kt2, 1, A0OFF); STAGE_A(kt2, 3, A0OFF); }, 0) \
    PHASE(A1OFF, B1OFF, 1, { STAGE_B(kt3, 0, B1OFF); STAGE_B(kt3, 1, B1OFF); }, 0) \
    PHASE(A1OFF, B1OFF, 2, { STAGE_B(kt3, 2, B1OFF); STAGE_B(kt3, 3, B1OFF); }, 0) \
    PHASE(A1OFF, B1OFF, 3, { STAGE_A(kt3, 0, A1OFF); STAGE_A(kt3, 2, A1OFF); }, 1) \
  }

__global__ __launch_bounds__(512, 2) void gemm_kernel(
    const signed char* __restrict__ A, const signed char* __restrict__ B,
    const float* __restrict__ scale, float* __restrict__ C) {
  __shared__ unsigned char lds[131072];     // 128 KiB

  const int tid = threadIdx.x;
  const int lane = tid & 63;
  const int wid = tid >> 6;                 // 0..7
  const int wmBase = (wid >> 2) * 128;      // wave M offset in tile
  const int wnBase = (wid & 3) * 64;        // wave N offset in tile

  // XCD-aware bijective swizzle: 512 blocks, 512 % 8 == 0
  const int bid = blockIdx.x;
  const int swz = (bid & 7) * 64 + (bid >> 3);
  const int tn = swz & 15;                  // 16 N-tiles
  const int tm = swz >> 4;                  // 32 M-tiles

  const signed char* Ag = A + (size_t)tm * 256 * (2 * K_IN);
  const signed char* Bg = B + (size_t)tn * 256 * K_IN;

  // per-lane staging source: row-in-unit = wid*8 + lane/8,
  // global 16B-chunk = (lane&7) ^ (lane>>3)  (inverse swizzle)
  const size_t laneOffA =
      (size_t)(wid * 8 + (lane >> 3)) * (2 * K_IN) + 16 * ((lane & 7) ^ (lane >> 3));
  const size_t laneOffB =
      (size_t)(wid * 8 + (lane >> 3)) * K_IN + 16 * ((lane & 7) ^ (lane >> 3));

  // fragment addressing (byte units)
  const int fr = lane & 15;
  const int fk16 = (lane >> 4) * 16;
  const int fswz = (fr & 7) * 16;

  int4v acc[8][4];
#pragma unroll
  for (int i = 0; i < 8; ++i)
#pragma unroll
    for (int j = 0; j < 4; ++j) acc[i][j] = (int4v){0, 0, 0, 0};
  int4v bf[4][2];

  // ---- prologue: K-tile 0 full + K-tile 1 B all, A u0,u2 (14 loads)
  STAGE_A(0, 0, A0OFF); STAGE_A(0, 1, A0OFF);
  STAGE_A(0, 2, A0OFF); STAGE_A(0, 3, A0OFF);
  STAGE_B(0, 0, B0OFF); STAGE_B(0, 1, B0OFF);
  STAGE_B(0, 2, B0OFF); STAGE_B(0, 3, B0OFF);
  STAGE_B(1, 0, B1OFF); STAGE_B(1, 1, B1OFF);
  STAGE_B(1, 2, B1OFF); STAGE_B(1, 3, B1OFF);
  STAGE_A(1, 0, A1OFF); STAGE_A(1, 2, A1OFF);
  asm volatile("s_waitcnt vmcnt(6)" ::: "memory");   // K-tile 0 landed
  __builtin_amdgcn_sched_barrier(0);
  __builtin_amdgcn_s_barrier();

  // hi slice: K-tiles 0..31
  for (int t = 0; t < 16; ++t) ITERBODY(t)

  // exact mid-point scaling: total = 128*hi_sum + lo_sum
#pragma unroll
  for (int i = 0; i < 8; ++i)
#pragma unroll
    for (int j = 0; j < 4; ++j) acc[i][j] <<= 7;

  // lo slice: K-tiles 32..63
  for (int t = 16; t < 32; ++t) ITERBODY(t)

  // epilogue: row = (lane>>4)*4 + r (+m*16), col = lane&15 (+n*16)
  const int r0 = tm * 256 + wmBase + ((lane >> 4) << 2);
  const int c0 = tn * 256 + wnBase + (lane & 15);
#pragma unroll
  for (int n = 0; n < 4; ++n) {
    float s = scale[c0 + n * 16] * (1.0f / 1024.0f);
#pragma unroll
    for (int m = 0; m < 8; ++m)
#pragma unroll
      for (int r = 0; r < 4; ++r)
        C[(size_t)(r0 + m * 16 + r) * N_OUT + c0 + n * 16] = (float)acc[m][n][r] * s;
  }
}

// correctness safety net if ws_size is too small for the staged path
__global__ void fallback_kernel(const float* __restrict__ x, const float* __restrict__ scale,
                                const float* __restrict__ zp, const int* __restrict__ q,
                                float* __restrict__ y) {
  int o = blockIdx.x * blockDim.x + threadIdx.x;
  int m = blockIdx.y;
  float z = zp[o];
  const int* qr = q + (size_t)o * K_IN;
  const float* xr = x + (size_t)m * K_IN;
  float acc = 0.f;
  for (int k = 0; k < K_IN; k += 4) {
    int4 qq = *(const int4*)(qr + k);
    float4 xx = *(const float4*)(xr + k);
    acc += xx.x * ((float)qq.x - z) + xx.y * ((float)qq.y - z)
         + xx.z * ((float)qq.z - z) + xx.w * ((float)qq.w - z);
  }
  y[(size_t)m * N_OUT + o] = acc * scale[o];
}

extern "C" void kernel_launch(void* const* d_in, const int* in_sizes, int n_in,
                              void* d_out, int out_size, void* d_ws, size_t ws_size,
                              hipStream_t stream) {
  const float* x     = (const float*)d_in[0];
  const float* scale = (const float*)d_in[1];
  const float* zp    = (const float*)d_in[2];
  const int*   q     = (const int*)d_in[3];
  float* y = (float*)d_out;
  const int M = in_sizes[0] / K_IN;          // 8192

  size_t wbytes = (size_t)N_OUT * K_IN;      // 16 MiB
  size_t abytes = (size_t)M * 2 * K_IN;      // 64 MiB
  if (ws_size >= wbytes + abytes && (M % 256) == 0) {
    signed char* W = (signed char*)d_ws;
    signed char* Abuf = W + wbytes;
    unsigned gw = (unsigned)(((size_t)N_OUT * K_IN) / (8 * 256));
    unsigned ga = (unsigned)(((size_t)M * K_IN) / (8 * 256));
    prep_w_kernel<<<gw, 256, 0, stream>>>(q, zp, W);
    prep_a_kernel<<<ga, 256, 0, stream>>>(x, Abuf);
    unsigned nblocks = (unsigned)((M / 256) * (N_OUT / 256));  // 512
    gemm_kernel<<<nblocks, 512, 0, stream>>>(Abuf, W, scale, y);
  } else {
    dim3 grid(N_OUT / 256, M);
    fallback_kernel<<<grid, 256, 0, stream>>>(x, scale, zp, q, y);
  }
}

// Round 8
// 269.050 us; speedup vs baseline: 3.2071x; 1.0330x over previous
//
#include <hip/hip_runtime.h>
#include <stdint.h>

typedef __attribute__((ext_vector_type(4))) int int4v;

#define K_IN 4096
#define N_OUT 4096
#define NKT 64             // K-tiles of 128 i8 elems (32 hi + 32 lo)

// W_i8[o][k] = (int8)(q[o][k] - zp[o])  (exact, in [-10,9])
__global__ void prep_w_kernel(const int* __restrict__ q, const float* __restrict__ zp,
                              signed char* __restrict__ W) {
  size_t t = (size_t)blockIdx.x * blockDim.x + threadIdx.x;
  size_t base = t * 8;
  int o = (int)(base >> 12);
  int z = (int)zp[o];                        // zp is an integral float
  int4 q0 = *(const int4*)(q + base);
  int4 q1 = *(const int4*)(q + base + 4);
  int v[8] = {q0.x, q0.y, q0.z, q0.w, q1.x, q1.y, q1.z, q1.w};
  union { signed char c[8]; uint64_t u; } pk;
#pragma unroll
  for (int j = 0; j < 8; ++j) pk.c[j] = (signed char)(v[j] - z);
  *(uint64_t*)(W + (size_t)o * K_IN + (base & 4095)) = pk.u;
}

// X14 = clamp(round(x*1024), +-8191) = 128*hi + lo; A[m][k]=hi, A[m][4096+k]=lo
__global__ void prep_a_kernel(const float* __restrict__ x, signed char* __restrict__ A) {
  size_t t = (size_t)blockIdx.x * blockDim.x + threadIdx.x;
  size_t base = t * 8;
  size_t m = base >> 12;
  int k = (int)(base & 4095);
  float4 x0 = *(const float4*)(x + base);
  float4 x1 = *(const float4*)(x + base + 4);
  float xs[8] = {x0.x, x0.y, x0.z, x0.w, x1.x, x1.y, x1.z, x1.w};
  union { signed char c[8]; uint64_t u; } hp, lp;
#pragma unroll
  for (int j = 0; j < 8; ++j) {
    int X = __float2int_rn(xs[j] * 1024.0f);
    X = X > 8191 ? 8191 : (X < -8191 ? -8191 : X);
    int hi = (X + 64) >> 7;                  // in [-64,64]
    int lo = X - (hi << 7);                  // in [-64,63]
    hp.c[j] = (signed char)hi;
    lp.c[j] = (signed char)lo;
  }
  size_t row = m * (size_t)(2 * K_IN);
  *(uint64_t*)(A + row + k) = hp.u;
  *(uint64_t*)(A + row + K_IN + k) = lp.u;
}

// ---------------------------------------------------------------------------
// 256x256 8-phase i8 GEMM, ONE barrier per phase + A-frag prefetch pipeline.
// Phase: {STAGE, lgkm0, MFMA(prefetched frags), prefetch f_{q+1}, [vmcnt6], bar}
// Cross-buffer phases (p1,p5) read their frags synchronously at phase start
// (right after the vmcnt(6)+barrier that collectively confirmed that buffer).
// WAR safety: reads drained by own lgkm0 before phase-end barrier; restages
// issued after a later barrier. Stage schedule identical to R7.
// ---------------------------------------------------------------------------
#define A0OFF 0
#define A1OFF 32768
#define B0OFF 65536
#define B1OFF 98304

#define STAGE_A(kt, u, ldsOff)                                                   \
  __builtin_amdgcn_global_load_lds(                                              \
      (const __attribute__((address_space(1))) void*)(Ag +                       \
          (size_t)(u) * 64 * (2 * K_IN) + (size_t)(kt) * 128 + laneOffA),        \
      (__attribute__((address_space(3))) void*)(lds + (ldsOff) + (u) * 8192 +    \
          wid * 1024), 16, 0, 0);

#define STAGE_B(kt, u, ldsOff)                                                   \
  __builtin_amdgcn_global_load_lds(                                              \
      (const __attribute__((address_space(1))) void*)(Bg +                       \
          (size_t)(u) * 64 * K_IN + (size_t)((kt) & 31) * 128 + laneOffB),       \
      (__attribute__((address_space(3))) void*)(lds + (ldsOff) + (u) * 8192 +    \
          wid * 1024), 16, 0, 0);

#define READ_A(dst, ABOFF, q)                                                    \
  _Pragma("unroll") for (int m2 = 0; m2 < 2; ++m2)                               \
    _Pragma("unroll") for (int kc = 0; kc < 2; ++kc)                             \
      dst[m2][kc] = *(const int4v*)&lds[(ABOFF) +                                \
          (wmBase + ((q) * 2 + m2) * 16 + fr) * 128 + ((kc * 64 + fk16) ^ fswz)];

#define READ_B(BBOFF)                                                            \
  _Pragma("unroll") for (int n = 0; n < 4; ++n)                                  \
    _Pragma("unroll") for (int kc = 0; kc < 2; ++kc)                             \
      bf[n][kc] = *(const int4v*)&lds[(BBOFF) +                                  \
          (wnBase + n * 16 + fr) * 128 + ((kc * 64 + fk16) ^ fswz)];

#define LGKM0 asm volatile("s_waitcnt lgkmcnt(0)" ::: "memory");                 \
  __builtin_amdgcn_sched_barrier(0);
#define VM6 asm volatile("s_waitcnt vmcnt(6)" ::: "memory");                     \
  __builtin_amdgcn_sched_barrier(0);
#define BAR __builtin_amdgcn_s_barrier();

#define MFMA16(src, q)                                                           \
  __builtin_amdgcn_s_setprio(1);                                                 \
  _Pragma("unroll") for (int kc = 0; kc < 2; ++kc)                               \
    _Pragma("unroll") for (int m2 = 0; m2 < 2; ++m2)                             \
      _Pragma("unroll") for (int n = 0; n < 4; ++n)                              \
        acc[(q) * 2 + m2][n] = __builtin_amdgcn_mfma_i32_16x16x64_i8(            \
            src[m2][kc], bf[n][kc], acc[(q) * 2 + m2][n], 0, 0, 0);              \
  __builtin_amdgcn_s_setprio(0);

#define ITERBODY(t)                                                              \
  {                                                                              \
    const int kt1 = 2 * (t) + 1;                                                 \
    const int kt2 = (2 * (t) + 2) & (NKT - 1);                                   \
    const int kt3 = (2 * (t) + 3) & (NKT - 1);                                   \
    /* p1 (cross-buffer: sync reads) */                                          \
    READ_A(aP, A0OFF, 0) READ_B(B0OFF)                                           \
    STAGE_A(kt1, 1, A1OFF) STAGE_A(kt1, 3, A1OFF)                                \
    LGKM0 MFMA16(aP, 0) READ_A(aQ, A0OFF, 1) BAR                                 \
    /* p2 */                                                                     \
    STAGE_B(kt2, 0, B0OFF) STAGE_B(kt2, 1, B0OFF)                                \
    LGKM0 MFMA16(aQ, 1) READ_A(aP, A0OFF, 2) BAR                                 \
    /* p3 */                                                                     \
    STAGE_B(kt2, 2, B0OFF) STAGE_B(kt2, 3, B0OFF)                                \
    LGKM0 MFMA16(aP, 2) READ_A(aQ, A0OFF, 3) BAR                                 \
    /* p4 */                                                                     \
    STAGE_A(kt2, 0, A0OFF) STAGE_A(kt2, 2, A0OFF)                                \
    LGKM0 MFMA16(aQ, 3) VM6 BAR                                                  \
    /* p5 (cross-buffer: sync reads) */                                          \
    READ_A(aP, A1OFF, 0) READ_B(B1OFF)                                           \
    STAGE_A(kt2, 1, A0OFF) STAGE_A(kt2, 3, A0OFF)                                \
    LGKM0 MFMA16(aP, 0) READ_A(aQ, A1OFF, 1) BAR                                 \
    /* p6 */                                                                     \
    STAGE_B(kt3, 0, B1OFF) STAGE_B(kt3, 1, B1OFF)                                \
    LGKM0 MFMA16(aQ, 1) READ_A(aP, A1OFF, 2) BAR                                 \
    /* p7 */                                                                     \
    STAGE_B(kt3, 2, B1OFF) STAGE_B(kt3, 3, B1OFF)                                \
    LGKM0 MFMA16(aP, 2) READ_A(aQ, A1OFF, 3) BAR                                 \
    /* p8 */                                                                     \
    STAGE_A(kt3, 0, A1OFF) STAGE_A(kt3, 2, A1OFF)                                \
    LGKM0 MFMA16(aQ, 3) VM6 BAR                                                  \
  }

__global__ __launch_bounds__(512, 2) void gemm_kernel(
    const signed char* __restrict__ A, const signed char* __restrict__ B,
    const float* __restrict__ scale, float* __restrict__ C) {
  __shared__ unsigned char lds[131072];     // 128 KiB

  const int tid = threadIdx.x;
  const int lane = tid & 63;
  const int wid = tid >> 6;                 // 0..7
  const int wmBase = (wid >> 2) * 128;      // wave M offset in tile
  const int wnBase = (wid & 3) * 64;        // wave N offset in tile

  // XCD-aware bijective swizzle: 512 blocks, 512 % 8 == 0
  const int bid = blockIdx.x;
  const int swz = (bid & 7) * 64 + (bid >> 3);
  const int tn = swz & 15;                  // 16 N-tiles
  const int tm = swz >> 4;                  // 32 M-tiles

  const signed char* Ag = A + (size_t)tm * 256 * (2 * K_IN);
  const signed char* Bg = B + (size_t)tn * 256 * K_IN;

  // per-lane staging source: row-in-unit = wid*8 + lane/8,
  // global 16B-chunk = (lane&7) ^ (lane>>3)  (inverse swizzle)
  const size_t laneOffA =
      (size_t)(wid * 8 + (lane >> 3)) * (2 * K_IN) + 16 * ((lane & 7) ^ (lane >> 3));
  const size_t laneOffB =
      (size_t)(wid * 8 + (lane >> 3)) * K_IN + 16 * ((lane & 7) ^ (lane >> 3));

  // fragment addressing (byte units)
  const int fr = lane & 15;
  const int fk16 = (lane >> 4) * 16;
  const int fswz = (fr & 7) * 16;

  int4v acc[8][4];
#pragma unroll
  for (int i = 0; i < 8; ++i)
#pragma unroll
    for (int j = 0; j < 4; ++j) acc[i][j] = (int4v){0, 0, 0, 0};
  int4v bf[4][2];
  int4v aP[2][2], aQ[2][2];                 // ping-pong A fragments

  // ---- prologue: K-tile 0 full + K-tile 1 B all, A u0,u2 (14 loads)
  STAGE_A(0, 0, A0OFF) STAGE_A(0, 1, A0OFF)
  STAGE_A(0, 2, A0OFF) STAGE_A(0, 3, A0OFF)
  STAGE_B(0, 0, B0OFF) STAGE_B(0, 1, B0OFF)
  STAGE_B(0, 2, B0OFF) STAGE_B(0, 3, B0OFF)
  STAGE_B(1, 0, B1OFF) STAGE_B(1, 1, B1OFF)
  STAGE_B(1, 2, B1OFF) STAGE_B(1, 3, B1OFF)
  STAGE_A(1, 0, A1OFF) STAGE_A(1, 2, A1OFF)
  VM6                                       // K-tile 0 (first 8 loads) landed
  BAR

  // hi slice: K-tiles 0..31
  for (int t = 0; t < 16; ++t) ITERBODY(t)

  // exact mid-point scaling: total = 128*hi_sum + lo_sum
#pragma unroll
  for (int i = 0; i < 8; ++i)
#pragma unroll
    for (int j = 0; j < 4; ++j) acc[i][j] <<= 7;

  // lo slice: K-tiles 32..63
  for (int t = 16; t < 32; ++t) ITERBODY(t)

  // epilogue: row = (lane>>4)*4 + r (+m*16), col = lane&15 (+n*16)
  const int r0 = tm * 256 + wmBase + ((lane >> 4) << 2);
  const int c0 = tn * 256 + wnBase + (lane & 15);
#pragma unroll
  for (int n = 0; n < 4; ++n) {
    float s = scale[c0 + n * 16] * (1.0f / 1024.0f);
#pragma unroll
    for (int m = 0; m < 8; ++m)
#pragma unroll
      for (int r = 0; r < 4; ++r)
        C[(size_t)(r0 + m * 16 + r) * N_OUT + c0 + n * 16] = (float)acc[m][n][r] * s;
  }
}

// correctness safety net if ws_size is too small for the staged path
__global__ void fallback_kernel(const float* __restrict__ x, const float* __restrict__ scale,
                                const float* __restrict__ zp, const int* __restrict__ q,
                                float* __restrict__ y) {
  int o = blockIdx.x * blockDim.x + threadIdx.x;
  int m = blockIdx.y;
  float z = zp[o];
  const int* qr = q + (size_t)o * K_IN;
  const float* xr = x + (size_t)m * K_IN;
  float acc = 0.f;
  for (int k = 0; k < K_IN; k += 4) {
    int4 qq = *(const int4*)(qr + k);
    float4 xx = *(const float4*)(xr + k);
    acc += xx.x * ((float)qq.x - z) + xx.y * ((float)qq.y - z)
         + xx.z * ((float)qq.z - z) + xx.w * ((float)qq.w - z);
  }
  y[(size_t)m * N_OUT + o] = acc * scale[o];
}

extern "C" void kernel_launch(void* const* d_in, const int* in_sizes, int n_in,
                              void* d_out, int out_size, void* d_ws, size_t ws_size,
                              hipStream_t stream) {
  const float* x     = (const float*)d_in[0];
  const float* scale = (const float*)d_in[1];
  const float* zp    = (const float*)d_in[2];
  const int*   q     = (const int*)d_in[3];
  float* y = (float*)d_out;
  const int M = in_sizes[0] / K_IN;          // 8192

  size_t wbytes = (size_t)N_OUT * K_IN;      // 16 MiB
  size_t abytes = (size_t)M * 2 * K_IN;      // 64 MiB
  if (ws_size >= wbytes + abytes && (M % 256) == 0) {
    signed char* W = (signed char*)d_ws;
    signed char* Abuf = W + wbytes;
    unsigned gw = (unsigned)(((size_t)N_OUT * K_IN) / (8 * 256));
    unsigned ga = (unsigned)(((size_t)M * K_IN) / (8 * 256));
    prep_w_kernel<<<gw, 256, 0, stream>>>(q, zp, W);
    prep_a_kernel<<<ga, 256, 0, stream>>>(x, Abuf);
    unsigned nblocks = (unsigned)((M / 256) * (N_OUT / 256));  // 512
    gemm_kernel<<<nblocks, 512, 0, stream>>>(Abuf, W, scale, y);
  } else {
    dim3 grid(N_OUT / 256, M);
    fallback_kernel<<<grid, 256, 0, stream>>>(x, scale, zp, q, y);
  }
}